// Round 1
// baseline (816.427 us; speedup 1.0000x reference)
//
#include <hip/hip_runtime.h>

#define N_NODES 100000
#define N_EDGES 3200000
#define QCH 32
#define DT_C 0.1f

// Kernel 1: out-degree of each node (float, matches segment_sum of ones)
__global__ void deg_kernel(const int* __restrict__ src,
                           float* __restrict__ deg, int E) {
    int e = blockIdx.x * blockDim.x + threadIdx.x;
    if (e < E) atomicAdd(&deg[src[e]], 1.0f);
}

// Kernel 2: per (edge, q) message scatter. trans accumulates outflow - inflow.
__global__ void edge_kernel(const float* __restrict__ f,
                            const float* __restrict__ w,
                            const int* __restrict__ src,
                            const int* __restrict__ dst,
                            const float* __restrict__ deg,
                            float* __restrict__ trans, int E) {
    long long t = (long long)blockIdx.x * blockDim.x + threadIdx.x;
    int e = (int)(t >> 5);
    int q = (int)(t & 31);
    if (e >= E) return;
    int s = src[e];
    int d = dst[e];
    float coef = w[e] / fmaxf(deg[s], 1.0f);
    float xi = 75.0f * (float)q * (1.0f / 31.0f);
    float fs = fmaxf(f[s * QCH + q], 0.0f);
    float fd = fmaxf(f[d * QCH + q], 0.0f);
    float msg = coef * xi * (fd - fs);
    atomicAdd(&trans[s * QCH + q],  msg);   // outflow at src
    atomicAdd(&trans[d * QCH + q], -msg);   // inflow at dst (subtracted)
}

// Kernel 3: in-place finalize. trans currently lives in `out`.
__global__ void final_kernel(const float* __restrict__ fdist,
                             const float* __restrict__ coll,
                             const float* __restrict__ srct,
                             float* __restrict__ out, int n) {
    int i = blockIdx.x * blockDim.x + threadIdx.x;
    if (i < n) {
        float fr = fmaxf(fdist[i], 0.0f);
        float t = out[i];
        out[i] = fmaxf(fr - DT_C * (t - coll[i] - srct[i]), 0.0f);
    }
}

extern "C" void kernel_launch(void* const* d_in, const int* in_sizes, int n_in,
                              void* d_out, int out_size, void* d_ws, size_t ws_size,
                              hipStream_t stream) {
    const float* f    = (const float*)d_in[0];  // [N, Q]
    const float* coll = (const float*)d_in[1];  // [N, Q]
    const float* srct = (const float*)d_in[2];  // [N, Q]
    const float* w    = (const float*)d_in[3];  // [E]
    const int*   src  = (const int*)d_in[4];    // [E]
    const int*   dst  = (const int*)d_in[5];    // [E]
    float* out = (float*)d_out;                 // [N, Q]
    float* deg = (float*)d_ws;                  // [N]

    const int N = N_NODES;
    const int E = N_EDGES;

    // zero degree buffer and output accumulator
    hipMemsetAsync(deg, 0, N * sizeof(float), stream);
    hipMemsetAsync(out, 0, (size_t)N * QCH * sizeof(float), stream);

    deg_kernel<<<(E + 255) / 256, 256, 0, stream>>>(src, deg, E);

    long long total = (long long)E * QCH;
    int blocks = (int)((total + 255) / 256);
    edge_kernel<<<blocks, 256, 0, stream>>>(f, w, src, dst, deg, out, E);

    int n = N * QCH;
    final_kernel<<<(n + 255) / 256, 256, 0, stream>>>(f, coll, srct, out, n);
}